// Round 17
// baseline (310.568 us; speedup 1.0000x reference)
//
#include <hip/hip_runtime.h>
#include <hip/hip_bf16.h>

#define NN 10000
#define EE 320000
#define EALL (EE + NN)   // 330000 edges incl. self loops
#define BG 64
#define AOUT 1024

#define WTOT 191361        // packed fp32 weight elements
#define NX (NN * 128)
#define NSF 262144         // sampled 16-bit halves for float-dtype probe
#define NSI 131072         // sampled index pairs for int-dtype probe

#define DRANGE 640         // dst range per CSR block (16 * 640 = 10240 >= 10000)
#define DNB 16
#define NSEG 64            // edge-stream segments (parallelism for CSR build)
#define ESEG 5157          // ceil(330000 / 64)

typedef __hip_bfloat16 bf16;
typedef __attribute__((ext_vector_type(8))) short bf16x8;   // 8 bf16 (4 VGPRs)
typedef __attribute__((ext_vector_type(4))) float f32x4;

__device__ __forceinline__ unsigned short f2bf(float f) {
    bf16 h = __float2bfloat16(f);
    return *reinterpret_cast<unsigned short*>(&h);
}
__device__ __forceinline__ float bf2f(unsigned short u) {
    bf16 h;
    *reinterpret_cast<unsigned short*>(&h) = u;
    return __bfloat162float(h);
}
__device__ __forceinline__ int f_isfp32(const int* flags) {
    return (flags[2] > 0 || flags[3] > 50000) ? 1 : 0;
}

__global__ void k_zero_i(int* p, int n) { int i = blockIdx.x * 256 + threadIdx.x; if (i < n) p[i] = 0; }

// ================= fused dtype detection (sampled, wave-reduced) =================
// flags: [1] int dtype (1=int32, 0=int64); [2] nan-pattern count; [3] zero-even-half count
__global__ void k_detect(const unsigned short* __restrict__ x, const unsigned int* __restrict__ ei,
                         int* __restrict__ flags) {
    int i = blockIdx.x * 256 + threadIdx.x;
    bool nanp = false, zp = false, odd = false;
    if (i < NSF) {
        unsigned short h = x[i];
        nanp = (h & 0x7F80u) == 0x7F80u;
        zp = ((i & 1) == 0) && (h == 0);
    } else if (i < NSF + NSI) {
        int j = i - NSF;
        odd = ei[2 * j + 1] != 0u;             // int64 high halves are all zero
    }
    unsigned long long bn = __ballot(nanp);
    unsigned long long bz = __ballot(zp);
    unsigned long long bo = __ballot(odd);
    if ((threadIdx.x & 63) == 0) {
        if (bn) atomicAdd(&flags[2], __popcll(bn));
        if (bz) atomicAdd(&flags[3], __popcll(bz));
        if (bo) atomicOr(&flags[1], 1);
    }
}

// ====== fused input conversion: fp32 weights + indices + x->bf16 + W1/W2/W3 ->bf16^T ======
struct WPtrs { const void* p[20]; };
__global__ void k_cvt_all(WPtrs wp, const void* __restrict__ xsrc,
                          const void* __restrict__ eisrc, const void* __restrict__ bsrc,
                          float* __restrict__ wf, int* __restrict__ ei32, int* __restrict__ b32,
                          unsigned short* __restrict__ x16,
                          unsigned short* __restrict__ w1t, unsigned short* __restrict__ w2t,
                          unsigned short* __restrict__ w3t,
                          const int* __restrict__ flags) {
    const int sz[20] = {32768,256,256,256,65536,256,256,256,16384,64,64,64,4096,64,65536,1024,4096,64,64,1};
    int i = blockIdx.x * 256 + threadIdx.x;
    const int ff = f_isfp32(flags), fi = flags[1];
    if (i < WTOT) {
        int seg = 0, off = 0;
        while (i - off >= sz[seg]) { off += sz[seg]; seg++; }
        const void* src = wp.p[seg];
        int k = i - off;
        wf[i] = ff ? ((const float*)src)[k] : __bfloat162float(((const bf16*)src)[k]);
        return;
    }
    i -= WTOT;
    if (i < 2 * EE) { ei32[i] = fi ? ((const int*)eisrc)[i] : (int)((const long long*)eisrc)[i]; return; }
    i -= 2 * EE;
    if (i < NN) { b32[i] = fi ? ((const int*)bsrc)[i] : (int)((const long long*)bsrc)[i]; return; }
    i -= NN;
    if (i < NX) {   // x -> bf16 (identity copy if already bf16 storage)
        x16[i] = ff ? f2bf(((const float*)xsrc)[i]) : ((const unsigned short*)xsrc)[i];
        return;
    }
    i -= NX;
    if (i < 32768) {  // W1 [128x256] -> w1t [256][128] bf16
        int k = i >> 8, c = i & 255;
        float v = ff ? ((const float*)wp.p[0])[i] : __bfloat162float(((const bf16*)wp.p[0])[i]);
        w1t[c * 128 + k] = f2bf(v);
        return;
    }
    i -= 32768;
    if (i < 65536) {  // W2 [256x256] -> w2t [256][256] bf16
        int k = i >> 8, c = i & 255;
        float v = ff ? ((const float*)wp.p[4])[i] : __bfloat162float(((const bf16*)wp.p[4])[i]);
        w2t[c * 256 + k] = f2bf(v);
        return;
    }
    i -= 65536;
    if (i < 16384) {  // W3 [256x64] -> w3t [64][256] bf16
        int k = i >> 6, c = i & 63;
        float v = ff ? ((const float*)wp.p[8])[i] : __bfloat162float(((const bf16*)wp.p[8])[i]);
        w3t[c * 256 + k] = f2bf(v);
    }
}

// ================= CSR phase A: per-(range,segment) partial histogram, LDS only =============
__global__ __launch_bounds__(256) void k_hist4(const int* __restrict__ ei, int* __restrict__ partial) {
    __shared__ int bins[DRANGE];
    const int r0 = blockIdx.x * DRANGE;
    const int sg = blockIdx.y;
    for (int i = threadIdx.x; i < DRANGE; i += 256) bins[i] = 0;
    __syncthreads();
    const int e1 = min(sg * ESEG + ESEG, EALL);
    for (int e = sg * ESEG + threadIdx.x; e < e1; e += 256) {
        int dst = (e < EE) ? ei[EE + e] : (e - EE);
        unsigned rel = dst - r0;
        if (rel < DRANGE) atomicAdd(&bins[rel], 1);
    }
    __syncthreads();
    for (int i = threadIdx.x; i < DRANGE; i += 256)
        partial[(blockIdx.x * NSEG + sg) * DRANGE + i] = bins[i];
}

// ================= CSR phase B1: per-bin segment reduction + local prefix (parallel) ========
__global__ void k_seg(const int* __restrict__ partial, int* __restrict__ deg,
                      int* __restrict__ segpre) {
    int bin = blockIdx.x * 256 + threadIdx.x;
    if (bin >= NN) return;
    int r = bin / DRANGE, rel = bin - r * DRANGE;
    int s = 0;
    for (int sg = 0; sg < NSEG; sg++) {
        int idx = (r * NSEG + sg) * DRANGE + rel;
        int v = partial[idx];
        segpre[idx] = s;
        s += v;
    }
    deg[bin] = s;
}

// ================= CSR phase B2: light single-block scan (coalesced deg) + gstart ===========
__global__ void k_scan4(const int* __restrict__ deg, int* __restrict__ rowstart,
                        const int* __restrict__ batch, int* __restrict__ gstart) {
    __shared__ int part[1024];
    const int t = threadIdx.x;
    if (t <= BG) {   // gstart[t] = first n with batch[n] >= t (batch is sorted)
        int lo = 0, hi = NN;
        while (lo < hi) { int mid = (lo + hi) >> 1; if (batch[mid] < t) lo = mid + 1; else hi = mid; }
        gstart[t] = lo;
    }
    const int base = t * 10;
    int local[10];
    int s = 0;
    for (int i = 0; i < 10; i++) {
        int idx = base + i;
        int v = (idx < NN) ? deg[idx] : 0;
        local[i] = s; s += v;
    }
    part[t] = s; __syncthreads();
    for (int off = 1; off < 1024; off <<= 1) {
        int v = (t >= off) ? part[t - off] : 0;
        __syncthreads();
        part[t] += v;
        __syncthreads();
    }
    int pre = (t == 0) ? 0 : part[t - 1];
    for (int i = 0; i < 10; i++) {
        int idx = base + i;
        if (idx < NN) rowstart[idx] = pre + local[i];
    }
    if (t == 1023) rowstart[NN] = part[1023];
}

// ================= CSR phase C: scatter, LDS cursors = rowstart + segpre ====================
__global__ __launch_bounds__(256) void k_scatter3(const int* __restrict__ ei,
                                                  const int* __restrict__ rowstart,
                                                  const int* __restrict__ segpre,
                                                  int* __restrict__ ssrc) {
    __shared__ int cur[DRANGE];
    const int r0 = blockIdx.x * DRANGE;
    const int sg = blockIdx.y;
    for (int i = threadIdx.x; i < DRANGE; i += 256) {
        int bin = r0 + i;
        cur[i] = (bin < NN) ? rowstart[bin] + segpre[(blockIdx.x * NSEG + sg) * DRANGE + i] : 0;
    }
    __syncthreads();
    const int e1 = min(sg * ESEG + ESEG, EALL);
    for (int e = sg * ESEG + threadIdx.x; e < e1; e += 256) {
        int dst = (e < EE) ? ei[EE + e] : (e - EE);
        unsigned rel = dst - r0;
        if (rel < DRANGE) {
            int src = (e < EE) ? ei[e] : dst;
            int pos = atomicAdd(&cur[rel], 1);
            ssrc[pos] = src;
        }
    }
}

// ====== MFMA GEMM: h = A(bf16) @ W(bf16^T), 64x64/block, 16x16x32 mfma, fused s,d ======
template<int K, int M>
__global__ __launch_bounds__(256) void k_gemm(const unsigned short* __restrict__ A16,
                                              const unsigned short* __restrict__ WT16,
                                              const float* __restrict__ asf,
                                              const float* __restrict__ adf,
                                              unsigned short* __restrict__ C16,
                                              float* __restrict__ sb, float* __restrict__ db) {
    constexpr int BK = 32;
    constexpr int H = M / 64;
    constexpr int LDW = 40;                    // row stride in bf16 units (80 B, 16B-aligned)
    __shared__ unsigned short As[64 * LDW];
    __shared__ unsigned short Bs[64 * LDW];
    const int row0 = blockIdx.x * 64;
    const int col0 = blockIdx.y * 64;
    const int hh = blockIdx.y;
    const int t = threadIdx.x;
    const int wv = t >> 6;
    const int lane = t & 63;
    const int m = lane & 15;
    const int q = lane >> 4;
    const int srow = t >> 2;          // staging row/col 0..63
    const int skoff = (t & 3) * 8;    // staging k offset (bf16 units)

    f32x4 acc[4] = {};

    for (int k0 = 0; k0 < K; k0 += BK) {
        {
            int grow = row0 + srow;
            uint4 av = make_uint4(0u, 0u, 0u, 0u);
            if (grow < NN) av = *(const uint4*)&A16[(size_t)grow * K + k0 + skoff];
            *(uint4*)&As[srow * LDW + skoff] = av;
            uint4 bv = *(const uint4*)&WT16[(size_t)(col0 + srow) * K + k0 + skoff];
            *(uint4*)&Bs[srow * LDW + skoff] = bv;
        }
        __syncthreads();
        bf16x8 af = *(const bf16x8*)&As[(16 * wv + m) * LDW + q * 8];
#pragma unroll
        for (int ct = 0; ct < 4; ct++) {
            bf16x8 bfv = *(const bf16x8*)&Bs[(16 * ct + m) * LDW + q * 8];
            acc[ct] = __builtin_amdgcn_mfma_f32_16x16x32_bf16(af, bfv, acc[ct], 0, 0, 0);
        }
        __syncthreads();
    }

    float asv[4], adv[4];
#pragma unroll
    for (int ct = 0; ct < 4; ct++) {
        asv[ct] = asf[hh * 64 + 16 * ct + m];
        adv[ct] = adf[hh * 64 + 16 * ct + m];
    }
#pragma unroll
    for (int reg = 0; reg < 4; reg++) {
        int row = row0 + 16 * wv + q * 4 + reg;
        float ps = 0.f, pd = 0.f;
        if (row < NN) {
#pragma unroll
            for (int ct = 0; ct < 4; ct++) {
                float v = acc[ct][reg];
                C16[(size_t)row * M + col0 + 16 * ct + m] = f2bf(v);
                ps += v * asv[ct];
                pd += v * adv[ct];
            }
        }
#pragma unroll
        for (int off = 1; off < 16; off <<= 1) {
            ps += __shfl_xor(ps, off);
            pd += __shfl_xor(pd, off);
        }
        if (m == 0 && row < NN) { sb[row * H + hh] = ps; db[row * H + hh] = pd; }
    }
}

// ===== softmax + aggregate per dst node; wide (8B/lane) gather with edge-parallelism =====
// 256 threads: thread = (epar, dim-group of 4). EPAR edges processed concurrently.
template<int H>
__global__ __launch_bounds__(256) void k_agg(const unsigned short* __restrict__ hbuf16,
                      const float* __restrict__ sb, const float* __restrict__ db,
                      const int* __restrict__ rowstart, const int* __restrict__ ssrc,
                      const float* __restrict__ bias, unsigned short* __restrict__ out16) {
    constexpr int M = H * 64;
    constexpr int NDG = M / 4;          // dim groups (4 dims each): 64 (H=4) or 16 (H=1)
    constexpr int LNDG = (H == 4) ? 6 : 4;
    constexpr int EPAR = 256 / NDG;     // edges in parallel: 4 or 16
    constexpr int LH = (H == 4) ? 2 : 0;
    const int n = blockIdx.x;
    const int tid = threadIdx.x;
    const int start = rowstart[n], end = rowstart[n + 1];
    __shared__ float red[256];
    __shared__ float sm[H], sws[H];
    __shared__ float wl[64 * H];
    __shared__ int srcl[64];
    __shared__ float redv[256 * 4];

    const int hh = tid & (H - 1);
    const float dn = db[n * H + hh];

    // phase 1: per-head max over edges (256-thread strided)
    float mymax = -3e38f;
    for (int p = start + (tid >> LH); p < end; p += (256 >> LH)) {
        float e = sb[ssrc[p] * H + hh] + dn;
        e = e > 0.f ? e : 0.2f * e;
        mymax = fmaxf(mymax, e);
    }
    red[tid] = mymax; __syncthreads();
    for (int off = 128; off >= H; off >>= 1) {
        if (tid < off) red[tid] = fmaxf(red[tid], red[tid + off]);
        __syncthreads();
    }
    if (tid < H) sm[tid] = red[tid];
    __syncthreads();
    const float mh = sm[hh];

    // phase 2: chunked exp weights + wide weighted gather
    const int dg = tid & (NDG - 1);
    const int epar = tid >> LNDG;
    const int d0 = dg * 4;
    const int h2 = d0 >> 6;
    float wsum = 0.f;
    float acc0 = 0.f, acc1 = 0.f, acc2 = 0.f, acc3 = 0.f;
    for (int c = start; c < end; c += 64) {
        const int cn = min(64, end - c);
        __syncthreads();
        if (tid < 64 * H) {
            int slot = tid >> LH;
            if (slot < cn) {
                int s = ssrc[c + slot];
                float e = sb[s * H + hh] + dn;
                e = e > 0.f ? e : 0.2f * e;
                float wv = __expf(e - mh);
                wl[slot * H + hh] = wv;
                wsum += wv;
                if (hh == 0) srcl[slot] = s;
            }
        }
        __syncthreads();
        for (int j = epar; j < cn; j += EPAR) {
            float wv = wl[j * H + h2];
            uint2 pk = *(const uint2*)&hbuf16[(size_t)srcl[j] * M + d0];
            acc0 += wv * bf2f((unsigned short)(pk.x & 0xFFFFu));
            acc1 += wv * bf2f((unsigned short)(pk.x >> 16));
            acc2 += wv * bf2f((unsigned short)(pk.y & 0xFFFFu));
            acc3 += wv * bf2f((unsigned short)(pk.y >> 16));
        }
    }
    __syncthreads();
    // wsum reduce (threads >= 64*H contributed nothing)
    red[tid] = (tid < 64 * H) ? wsum : 0.f;
    __syncthreads();
    for (int off = 128; off >= H; off >>= 1) {
        if (tid < off) red[tid] += red[tid + off];
        __syncthreads();
    }
    if (tid < H) sws[tid] = red[tid];

    // cross-epar reduction of partial sums
    *(float4*)&redv[tid * 4] = make_float4(acc0, acc1, acc2, acc3);
    __syncthreads();
    if (epar == 0) {
        float o0 = 0.f, o1 = 0.f, o2 = 0.f, o3 = 0.f;
#pragma unroll
        for (int e2 = 0; e2 < EPAR; e2++) {
            float4 v = *(const float4*)&redv[(e2 * NDG + dg) * 4];
            o0 += v.x; o1 += v.y; o2 += v.z; o3 += v.w;
        }
        float ws = sws[h2];
        ushort4 r;
        r.x = f2bf(fmaxf(o0 / ws + bias[d0 + 0], 0.f));
        r.y = f2bf(fmaxf(o1 / ws + bias[d0 + 1], 0.f));
        r.z = f2bf(fmaxf(o2 / ws + bias[d0 + 2], 0.f));
        r.w = f2bf(fmaxf(o3 / ws + bias[d0 + 3], 0.f));
        *(ushort4*)&out16[(size_t)n * M + d0] = r;
    }
}

// ====== fused: global mean pool (bf16 feat) -> hidden -> actor/critic out (one blk/graph) ===
__global__ __launch_bounds__(256) void k_final(const unsigned short* __restrict__ feat16,
                                               const int* __restrict__ gstart,
                                               const float* __restrict__ Wa1, const float* __restrict__ ba1,
                                               const float* __restrict__ Wc1, const float* __restrict__ bc1,
                                               const float* __restrict__ Wa2, const float* __restrict__ ba2,
                                               const float* __restrict__ Wc2, const float* __restrict__ bc2,
                                               float* __restrict__ out) {
    __shared__ float red[256];
    __shared__ float p[64];
    __shared__ float a[64], cc[64];
    const int g = blockIdx.x, t = threadIdx.x;
    const int d = t & 63, c = t >> 6;
    const int s = gstart[g], e = gstart[g + 1];
    float acc = 0.f;
    for (int n = s + c; n < e; n += 4) acc += bf2f(feat16[(size_t)n * 64 + d]);
    red[t] = acc; __syncthreads();
    if (c == 0) p[d] = (red[d] + red[64 + d] + red[128 + d] + red[192 + d])
                       / fmaxf((float)(e - s), 1.f);
    __syncthreads();
    if (t < 128) {
        int j = t & 63;
        const float* W  = (t < 64) ? Wa1 : Wc1;
        const float* bb = (t < 64) ? ba1 : bc1;
        float h = 0.f;
#pragma unroll 8
        for (int k = 0; k < 64; k++) h += p[k] * W[k * 64 + j];
        h = fmaxf(h + bb[j], 0.f);
        if (t < 64) a[j] = h; else cc[j] = h;
    }
    __syncthreads();
    float o[4] = {0.f, 0.f, 0.f, 0.f};
    for (int k = 0; k < 64; k++) {
        float ak = a[k];
#pragma unroll
        for (int q = 0; q < 4; q++) o[q] += ak * Wa2[k * AOUT + t + 256 * q];
    }
#pragma unroll
    for (int q = 0; q < 4; q++)
        out[g * AOUT + t + 256 * q] = tanhf(o[q] + ba2[t + 256 * q]);
    if (t == 0) {
        float v = 0.f;
        for (int k = 0; k < 64; k++) v += cc[k] * Wc2[k];
        out[BG * AOUT + g] = v + bc2[0];
    }
}

extern "C" void kernel_launch(void* const* d_in, const int* in_sizes, int n_in,
                              void* d_out, int out_size, void* d_ws, size_t ws_size,
                              hipStream_t stream) {
    float* out = (float*)d_out;

    char* w = (char*)d_ws;
    auto alloc = [&](size_t bytes) { void* p = (void*)w; w += (bytes + 255) & ~size_t(255); return p; };
    float* wf      = (float*)alloc((size_t)WTOT * 4);
    int*   ei32    = (int*)alloc((size_t)2 * EE * 4);
    int*   b32     = (int*)alloc((size_t)NN * 4);
    unsigned short* x16    = (unsigned short*)alloc((size_t)NX * 2);
    unsigned short* w1t    = (unsigned short*)alloc((size_t)32768 * 2);
    unsigned short* w2t    = (unsigned short*)alloc((size_t)65536 * 2);
    unsigned short* w3t    = (unsigned short*)alloc((size_t)16384 * 2);
    unsigned short* actA16 = (unsigned short*)alloc((size_t)NN * 256 * 2);  // gemm out
    unsigned short* actB16 = (unsigned short*)alloc((size_t)NN * 256 * 2);  // agg out
    float* sb      = (float*)alloc((size_t)NN * 4 * 4);
    float* db      = (float*)alloc((size_t)NN * 4 * 4);
    int*   partial = (int*)alloc((size_t)DNB * NSEG * DRANGE * 4);
    int*   segpre  = (int*)alloc((size_t)DNB * NSEG * DRANGE * 4);
    int*   deg     = (int*)alloc((size_t)NN * 4);
    int*   flags   = (int*)alloc(64);
    int*   rowstart= (int*)alloc((size_t)(NN + 1) * 4);
    int*   ssrc    = (int*)alloc((size_t)EALL * 4);
    int*   gstart  = (int*)alloc((size_t)(BG + 1) * 4);

    // ---- zero flags ----
    k_zero_i<<<1, 64, 0, stream>>>(flags, 16);

    // ---- fused dtype detection (decision computed inline by consumers) ----
    k_detect<<<(NSF + NSI + 255) / 256, 256, 0, stream>>>(
        (const unsigned short*)d_in[0], (const unsigned int*)d_in[1], flags);

    // ---- fused input conversion ----
    WPtrs wp;
    for (int s = 0; s < 20; s++) wp.p[s] = d_in[3 + s];
    const int CVT_TOT = WTOT + 2 * EE + NN + NX + 32768 + 65536 + 16384;
    k_cvt_all<<<(CVT_TOT + 255) / 256, 256, 0, stream>>>(
        wp, d_in[0], d_in[1], d_in[2], wf, ei32, b32, x16, w1t, w2t, w3t, flags);

    const int wsz[20] = {32768,256,256,256,65536,256,256,256,16384,64,64,64,4096,64,65536,1024,4096,64,64,1};
    int woff[20]; int acc = 0;
    for (int s = 0; s < 20; s++) { woff[s] = acc; acc += wsz[s]; }
    const float *as1f = wf + woff[1], *ad1f = wf + woff[2], *b1f = wf + woff[3];
    const float *as2f = wf + woff[5], *ad2f = wf + woff[6], *b2f = wf + woff[7];
    const float *as3f = wf + woff[9], *ad3f = wf + woff[10], *b3f = wf + woff[11];
    const float *Wa1f = wf + woff[12], *ba1f = wf + woff[13], *Wa2f = wf + woff[14], *ba2f = wf + woff[15];
    const float *Wc1f = wf + woff[16], *bc1f = wf + woff[17], *Wc2f = wf + woff[18], *bc2f = wf + woff[19];

    // ---- CSR + graph boundaries (LDS atomics only, 16x replication) ----
    k_hist4<<<dim3(DNB, NSEG), 256, 0, stream>>>(ei32, partial);
    k_seg<<<(NN + 255) / 256, 256, 0, stream>>>(partial, deg, segpre);
    k_scan4<<<1, 1024, 0, stream>>>(deg, rowstart, b32, gstart);
    k_scatter3<<<dim3(DNB, NSEG), 256, 0, stream>>>(ei32, rowstart, segpre, ssrc);

    // ---- Layer 1: in 128 (x16), heads=4, out 64, concat ----
    k_gemm<128, 256><<<dim3(157, 4), 256, 0, stream>>>(x16, w1t, as1f, ad1f, actA16, sb, db);
    k_agg<4><<<NN, 256, 0, stream>>>(actA16, sb, db, rowstart, ssrc, b1f, actB16);

    // ---- Layer 2: in 256 (bf16), heads=4, out 64, concat ----
    k_gemm<256, 256><<<dim3(157, 4), 256, 0, stream>>>(actB16, w2t, as2f, ad2f, actA16, sb, db);
    k_agg<4><<<NN, 256, 0, stream>>>(actA16, sb, db, rowstart, ssrc, b2f, actB16);

    // ---- Layer 3: in 256 (bf16), heads=1, out 64 ----
    k_gemm<256, 64><<<dim3(157, 1), 256, 0, stream>>>(actB16, w3t, as3f, ad3f, actA16, sb, db);
    k_agg<1><<<NN, 256, 0, stream>>>(actA16, sb, db, rowstart, ssrc, b3f, actB16);

    // ---- fused pool + heads (bf16 features) ----
    k_final<<<BG, 256, 0, stream>>>(actB16, gstart,
                                    Wa1f, ba1f, Wc1f, bc1f, Wa2f, ba2f, Wc2f, bc2f, out);
}

// Round 18
// 306.911 us; speedup vs baseline: 1.0119x; 1.0119x over previous
//
#include <hip/hip_runtime.h>
#include <hip/hip_bf16.h>

#define NN 10000
#define EE 320000
#define EALL (EE + NN)   // 330000 edges incl. self loops
#define BG 64
#define AOUT 1024

#define WTOT 191361        // packed fp32 weight elements
#define NX (NN * 128)
#define NSF 262144         // sampled 16-bit halves for float-dtype probe
#define NSI 131072         // sampled index pairs for int-dtype probe

#define DRANGE 640         // dst range per CSR block (16 * 640 = 10240 >= 10000)
#define DNB 16
#define NSEG 64            // edge-stream segments (parallelism for CSR build)
#define ESEG 5157          // ceil(330000 / 64)

typedef __hip_bfloat16 bf16;
typedef __attribute__((ext_vector_type(8))) short bf16x8;   // 8 bf16 (4 VGPRs)
typedef __attribute__((ext_vector_type(4))) float f32x4;

__device__ __forceinline__ unsigned short f2bf(float f) {
    bf16 h = __float2bfloat16(f);
    return *reinterpret_cast<unsigned short*>(&h);
}
__device__ __forceinline__ float bf2f(unsigned short u) {
    bf16 h;
    *reinterpret_cast<unsigned short*>(&h) = u;
    return __bfloat162float(h);
}
__device__ __forceinline__ int f_isfp32(const int* flags) {
    return (flags[2] > 0 || flags[3] > 50000) ? 1 : 0;
}

__global__ void k_zero_i(int* p, int n) { int i = blockIdx.x * 256 + threadIdx.x; if (i < n) p[i] = 0; }

// ================= fused dtype detection (sampled, wave-reduced) =================
// flags: [1] int dtype (1=int32, 0=int64); [2] nan-pattern count; [3] zero-even-half count
__global__ void k_detect(const unsigned short* __restrict__ x, const unsigned int* __restrict__ ei,
                         int* __restrict__ flags) {
    int i = blockIdx.x * 256 + threadIdx.x;
    bool nanp = false, zp = false, odd = false;
    if (i < NSF) {
        unsigned short h = x[i];
        nanp = (h & 0x7F80u) == 0x7F80u;
        zp = ((i & 1) == 0) && (h == 0);
    } else if (i < NSF + NSI) {
        int j = i - NSF;
        odd = ei[2 * j + 1] != 0u;             // int64 high halves are all zero
    }
    unsigned long long bn = __ballot(nanp);
    unsigned long long bz = __ballot(zp);
    unsigned long long bo = __ballot(odd);
    if ((threadIdx.x & 63) == 0) {
        if (bn) atomicAdd(&flags[2], __popcll(bn));
        if (bz) atomicAdd(&flags[3], __popcll(bz));
        if (bo) atomicOr(&flags[1], 1);
    }
}

// ====== fused input conversion: fp32 weights + indices + x->bf16 + W1/W2/W3 ->bf16^T ======
struct WPtrs { const void* p[20]; };
__global__ void k_cvt_all(WPtrs wp, const void* __restrict__ xsrc,
                          const void* __restrict__ eisrc, const void* __restrict__ bsrc,
                          float* __restrict__ wf, int* __restrict__ ei32, int* __restrict__ b32,
                          unsigned short* __restrict__ x16,
                          unsigned short* __restrict__ w1t, unsigned short* __restrict__ w2t,
                          unsigned short* __restrict__ w3t,
                          const int* __restrict__ flags) {
    const int sz[20] = {32768,256,256,256,65536,256,256,256,16384,64,64,64,4096,64,65536,1024,4096,64,64,1};
    int i = blockIdx.x * 256 + threadIdx.x;
    const int ff = f_isfp32(flags), fi = flags[1];
    if (i < WTOT) {
        int seg = 0, off = 0;
        while (i - off >= sz[seg]) { off += sz[seg]; seg++; }
        const void* src = wp.p[seg];
        int k = i - off;
        wf[i] = ff ? ((const float*)src)[k] : __bfloat162float(((const bf16*)src)[k]);
        return;
    }
    i -= WTOT;
    if (i < 2 * EE) { ei32[i] = fi ? ((const int*)eisrc)[i] : (int)((const long long*)eisrc)[i]; return; }
    i -= 2 * EE;
    if (i < NN) { b32[i] = fi ? ((const int*)bsrc)[i] : (int)((const long long*)bsrc)[i]; return; }
    i -= NN;
    if (i < NX) {   // x -> bf16 (identity copy if already bf16 storage)
        x16[i] = ff ? f2bf(((const float*)xsrc)[i]) : ((const unsigned short*)xsrc)[i];
        return;
    }
    i -= NX;
    if (i < 32768) {  // W1 [128x256] -> w1t [256][128] bf16
        int k = i >> 8, c = i & 255;
        float v = ff ? ((const float*)wp.p[0])[i] : __bfloat162float(((const bf16*)wp.p[0])[i]);
        w1t[c * 128 + k] = f2bf(v);
        return;
    }
    i -= 32768;
    if (i < 65536) {  // W2 [256x256] -> w2t [256][256] bf16
        int k = i >> 8, c = i & 255;
        float v = ff ? ((const float*)wp.p[4])[i] : __bfloat162float(((const bf16*)wp.p[4])[i]);
        w2t[c * 256 + k] = f2bf(v);
        return;
    }
    i -= 65536;
    if (i < 16384) {  // W3 [256x64] -> w3t [64][256] bf16
        int k = i >> 6, c = i & 63;
        float v = ff ? ((const float*)wp.p[8])[i] : __bfloat162float(((const bf16*)wp.p[8])[i]);
        w3t[c * 256 + k] = f2bf(v);
    }
}

// ================= CSR phase A: per-(range,segment) partial histogram, LDS only =============
__global__ __launch_bounds__(256) void k_hist4(const int* __restrict__ ei, int* __restrict__ partial) {
    __shared__ int bins[DRANGE];
    const int r0 = blockIdx.x * DRANGE;
    const int sg = blockIdx.y;
    for (int i = threadIdx.x; i < DRANGE; i += 256) bins[i] = 0;
    __syncthreads();
    const int e1 = min(sg * ESEG + ESEG, EALL);
    for (int e = sg * ESEG + threadIdx.x; e < e1; e += 256) {
        int dst = (e < EE) ? ei[EE + e] : (e - EE);
        unsigned rel = dst - r0;
        if (rel < DRANGE) atomicAdd(&bins[rel], 1);
    }
    __syncthreads();
    for (int i = threadIdx.x; i < DRANGE; i += 256)
        partial[(blockIdx.x * NSEG + sg) * DRANGE + i] = bins[i];
}

// ================= CSR phase B1: per-bin segment reduction + local prefix (parallel) ========
__global__ void k_seg(const int* __restrict__ partial, int* __restrict__ deg,
                      int* __restrict__ segpre) {
    int bin = blockIdx.x * 256 + threadIdx.x;
    if (bin >= NN) return;
    int r = bin / DRANGE, rel = bin - r * DRANGE;
    int s = 0;
    for (int sg = 0; sg < NSEG; sg++) {
        int idx = (r * NSEG + sg) * DRANGE + rel;
        int v = partial[idx];
        segpre[idx] = s;
        s += v;
    }
    deg[bin] = s;
}

// ================= CSR phase B2: light single-block scan (coalesced deg) + gstart ===========
__global__ void k_scan4(const int* __restrict__ deg, int* __restrict__ rowstart,
                        const int* __restrict__ batch, int* __restrict__ gstart) {
    __shared__ int part[1024];
    const int t = threadIdx.x;
    if (t <= BG) {   // gstart[t] = first n with batch[n] >= t (batch is sorted)
        int lo = 0, hi = NN;
        while (lo < hi) { int mid = (lo + hi) >> 1; if (batch[mid] < t) lo = mid + 1; else hi = mid; }
        gstart[t] = lo;
    }
    const int base = t * 10;
    int local[10];
    int s = 0;
    for (int i = 0; i < 10; i++) {
        int idx = base + i;
        int v = (idx < NN) ? deg[idx] : 0;
        local[i] = s; s += v;
    }
    part[t] = s; __syncthreads();
    for (int off = 1; off < 1024; off <<= 1) {
        int v = (t >= off) ? part[t - off] : 0;
        __syncthreads();
        part[t] += v;
        __syncthreads();
    }
    int pre = (t == 0) ? 0 : part[t - 1];
    for (int i = 0; i < 10; i++) {
        int idx = base + i;
        if (idx < NN) rowstart[idx] = pre + local[i];
    }
    if (t == 1023) rowstart[NN] = part[1023];
}

// ================= CSR phase C: scatter, LDS cursors = rowstart + segpre ====================
__global__ __launch_bounds__(256) void k_scatter3(const int* __restrict__ ei,
                                                  const int* __restrict__ rowstart,
                                                  const int* __restrict__ segpre,
                                                  int* __restrict__ ssrc) {
    __shared__ int cur[DRANGE];
    const int r0 = blockIdx.x * DRANGE;
    const int sg = blockIdx.y;
    for (int i = threadIdx.x; i < DRANGE; i += 256) {
        int bin = r0 + i;
        cur[i] = (bin < NN) ? rowstart[bin] + segpre[(blockIdx.x * NSEG + sg) * DRANGE + i] : 0;
    }
    __syncthreads();
    const int e1 = min(sg * ESEG + ESEG, EALL);
    for (int e = sg * ESEG + threadIdx.x; e < e1; e += 256) {
        int dst = (e < EE) ? ei[EE + e] : (e - EE);
        unsigned rel = dst - r0;
        if (rel < DRANGE) {
            int src = (e < EE) ? ei[e] : dst;
            int pos = atomicAdd(&cur[rel], 1);
            ssrc[pos] = src;
        }
    }
}

// ====== MFMA GEMM: h = A(bf16) @ W(bf16^T), 64x64/block, 16x16x32 mfma, fused s,d ======
template<int K, int M>
__global__ __launch_bounds__(256) void k_gemm(const unsigned short* __restrict__ A16,
                                              const unsigned short* __restrict__ WT16,
                                              const float* __restrict__ asf,
                                              const float* __restrict__ adf,
                                              unsigned short* __restrict__ C16,
                                              float* __restrict__ sb, float* __restrict__ db) {
    constexpr int BK = 32;
    constexpr int H = M / 64;
    constexpr int LDW = 40;                    // row stride in bf16 units (80 B, 16B-aligned)
    __shared__ unsigned short As[64 * LDW];
    __shared__ unsigned short Bs[64 * LDW];
    const int row0 = blockIdx.x * 64;
    const int col0 = blockIdx.y * 64;
    const int hh = blockIdx.y;
    const int t = threadIdx.x;
    const int wv = t >> 6;
    const int lane = t & 63;
    const int m = lane & 15;
    const int q = lane >> 4;
    const int srow = t >> 2;          // staging row/col 0..63
    const int skoff = (t & 3) * 8;    // staging k offset (bf16 units)

    f32x4 acc[4] = {};

    for (int k0 = 0; k0 < K; k0 += BK) {
        {
            int grow = row0 + srow;
            uint4 av = make_uint4(0u, 0u, 0u, 0u);
            if (grow < NN) av = *(const uint4*)&A16[(size_t)grow * K + k0 + skoff];
            *(uint4*)&As[srow * LDW + skoff] = av;
            uint4 bv = *(const uint4*)&WT16[(size_t)(col0 + srow) * K + k0 + skoff];
            *(uint4*)&Bs[srow * LDW + skoff] = bv;
        }
        __syncthreads();
        bf16x8 af = *(const bf16x8*)&As[(16 * wv + m) * LDW + q * 8];
#pragma unroll
        for (int ct = 0; ct < 4; ct++) {
            bf16x8 bfv = *(const bf16x8*)&Bs[(16 * ct + m) * LDW + q * 8];
            acc[ct] = __builtin_amdgcn_mfma_f32_16x16x32_bf16(af, bfv, acc[ct], 0, 0, 0);
        }
        __syncthreads();
    }

    float asv[4], adv[4];
#pragma unroll
    for (int ct = 0; ct < 4; ct++) {
        asv[ct] = asf[hh * 64 + 16 * ct + m];
        adv[ct] = adf[hh * 64 + 16 * ct + m];
    }
#pragma unroll
    for (int reg = 0; reg < 4; reg++) {
        int row = row0 + 16 * wv + q * 4 + reg;
        float ps = 0.f, pd = 0.f;
        if (row < NN) {
#pragma unroll
            for (int ct = 0; ct < 4; ct++) {
                float v = acc[ct][reg];
                C16[(size_t)row * M + col0 + 16 * ct + m] = f2bf(v);
                ps += v * asv[ct];
                pd += v * adv[ct];
            }
        }
#pragma unroll
        for (int off = 1; off < 16; off <<= 1) {
            ps += __shfl_xor(ps, off);
            pd += __shfl_xor(pd, off);
        }
        if (m == 0 && row < NN) { sb[row * H + hh] = ps; db[row * H + hh] = pd; }
    }
}

// ===== softmax + aggregate per dst node (one block per node); bf16 gather, bf16 out =====
// (R16 version — measured best; R17's edge-parallel variant regressed)
template<int H>
__global__ void k_agg(const unsigned short* __restrict__ hbuf16, const float* __restrict__ sb,
                      const float* __restrict__ db, const int* __restrict__ rowstart,
                      const int* __restrict__ ssrc, const float* __restrict__ bias,
                      unsigned short* __restrict__ out16) {
    constexpr int M = H * 64;
    constexpr int LH = (H == 4) ? 2 : 0;
    const int n = blockIdx.x;
    const int tid = threadIdx.x;
    const int start = rowstart[n], end = rowstart[n + 1];
    const int slot = tid >> LH;
    const int hh = tid & (H - 1);
    const int h2 = tid >> 6;
    __shared__ float red[M];
    __shared__ float sm[H], sws[H];
    __shared__ float wl[64 * H];
    __shared__ int srcl[64];
    const float dn = db[n * H + hh];

    float mymax = -3e38f;
    for (int p = start + slot; p < end; p += 64) {
        float e = sb[ssrc[p] * H + hh] + dn;
        e = e > 0.f ? e : 0.2f * e;
        mymax = fmaxf(mymax, e);
    }
    red[tid] = mymax; __syncthreads();
    for (int off = M / 2; off >= H; off >>= 1) {
        if (tid < off) red[tid] = fmaxf(red[tid], red[tid + off]);
        __syncthreads();
    }
    if (tid < H) sm[tid] = red[tid];
    __syncthreads();
    const float mh = sm[hh];

    float wsum = 0.f;
    float acc = 0.f;
    for (int c = start; c < end; c += 64) {
        const int cn = min(64, end - c);
        __syncthreads();
        if (slot < cn) {
            int s = ssrc[c + slot];
            float e = sb[s * H + hh] + dn;
            e = e > 0.f ? e : 0.2f * e;
            float wv = __expf(e - mh);
            wl[slot * H + hh] = wv;
            wsum += wv;
            if (hh == 0) srcl[slot] = s;
        }
        __syncthreads();
#pragma unroll 4
        for (int j = 0; j < cn; j++) {
            acc += wl[j * H + h2] * bf2f(hbuf16[(size_t)srcl[j] * M + tid]);
        }
    }
    __syncthreads();
    red[tid] = wsum; __syncthreads();
    for (int off = M / 2; off >= H; off >>= 1) {
        if (tid < off) red[tid] += red[tid + off];
        __syncthreads();
    }
    if (tid < H) sws[tid] = red[tid];
    __syncthreads();

    float o = acc / sws[h2] + bias[tid];
    out16[(size_t)n * M + tid] = f2bf(fmaxf(o, 0.f));
}

// ====== fused: global mean pool (bf16 feat) -> hidden -> actor/critic out (one blk/graph) ===
__global__ __launch_bounds__(256) void k_final(const unsigned short* __restrict__ feat16,
                                               const int* __restrict__ gstart,
                                               const float* __restrict__ Wa1, const float* __restrict__ ba1,
                                               const float* __restrict__ Wc1, const float* __restrict__ bc1,
                                               const float* __restrict__ Wa2, const float* __restrict__ ba2,
                                               const float* __restrict__ Wc2, const float* __restrict__ bc2,
                                               float* __restrict__ out) {
    __shared__ float red[256];
    __shared__ float p[64];
    __shared__ float a[64], cc[64];
    const int g = blockIdx.x, t = threadIdx.x;
    const int d = t & 63, c = t >> 6;
    const int s = gstart[g], e = gstart[g + 1];
    float acc = 0.f;
    for (int n = s + c; n < e; n += 4) acc += bf2f(feat16[(size_t)n * 64 + d]);
    red[t] = acc; __syncthreads();
    if (c == 0) p[d] = (red[d] + red[64 + d] + red[128 + d] + red[192 + d])
                       / fmaxf((float)(e - s), 1.f);
    __syncthreads();
    if (t < 128) {
        int j = t & 63;
        const float* W  = (t < 64) ? Wa1 : Wc1;
        const float* bb = (t < 64) ? ba1 : bc1;
        float h = 0.f;
#pragma unroll 8
        for (int k = 0; k < 64; k++) h += p[k] * W[k * 64 + j];
        h = fmaxf(h + bb[j], 0.f);
        if (t < 64) a[j] = h; else cc[j] = h;
    }
    __syncthreads();
    float o[4] = {0.f, 0.f, 0.f, 0.f};
    for (int k = 0; k < 64; k++) {
        float ak = a[k];
#pragma unroll
        for (int q = 0; q < 4; q++) o[q] += ak * Wa2[k * AOUT + t + 256 * q];
    }
#pragma unroll
    for (int q = 0; q < 4; q++)
        out[g * AOUT + t + 256 * q] = tanhf(o[q] + ba2[t + 256 * q]);
    if (t == 0) {
        float v = 0.f;
        for (int k = 0; k < 64; k++) v += cc[k] * Wc2[k];
        out[BG * AOUT + g] = v + bc2[0];
    }
}

extern "C" void kernel_launch(void* const* d_in, const int* in_sizes, int n_in,
                              void* d_out, int out_size, void* d_ws, size_t ws_size,
                              hipStream_t stream) {
    float* out = (float*)d_out;

    char* w = (char*)d_ws;
    auto alloc = [&](size_t bytes) { void* p = (void*)w; w += (bytes + 255) & ~size_t(255); return p; };
    float* wf      = (float*)alloc((size_t)WTOT * 4);
    int*   ei32    = (int*)alloc((size_t)2 * EE * 4);
    int*   b32     = (int*)alloc((size_t)NN * 4);
    unsigned short* x16    = (unsigned short*)alloc((size_t)NX * 2);
    unsigned short* w1t    = (unsigned short*)alloc((size_t)32768 * 2);
    unsigned short* w2t    = (unsigned short*)alloc((size_t)65536 * 2);
    unsigned short* w3t    = (unsigned short*)alloc((size_t)16384 * 2);
    unsigned short* actA16 = (unsigned short*)alloc((size_t)NN * 256 * 2);  // gemm out
    unsigned short* actB16 = (unsigned short*)alloc((size_t)NN * 256 * 2);  // agg out
    float* sb      = (float*)alloc((size_t)NN * 4 * 4);
    float* db      = (float*)alloc((size_t)NN * 4 * 4);
    int*   partial = (int*)alloc((size_t)DNB * NSEG * DRANGE * 4);
    int*   segpre  = (int*)alloc((size_t)DNB * NSEG * DRANGE * 4);
    int*   deg     = (int*)alloc((size_t)NN * 4);
    int*   flags   = (int*)alloc(64);
    int*   rowstart= (int*)alloc((size_t)(NN + 1) * 4);
    int*   ssrc    = (int*)alloc((size_t)EALL * 4);
    int*   gstart  = (int*)alloc((size_t)(BG + 1) * 4);

    // ---- zero flags ----
    k_zero_i<<<1, 64, 0, stream>>>(flags, 16);

    // ---- fused dtype detection (decision computed inline by consumers) ----
    k_detect<<<(NSF + NSI + 255) / 256, 256, 0, stream>>>(
        (const unsigned short*)d_in[0], (const unsigned int*)d_in[1], flags);

    // ---- fused input conversion ----
    WPtrs wp;
    for (int s = 0; s < 20; s++) wp.p[s] = d_in[3 + s];
    const int CVT_TOT = WTOT + 2 * EE + NN + NX + 32768 + 65536 + 16384;
    k_cvt_all<<<(CVT_TOT + 255) / 256, 256, 0, stream>>>(
        wp, d_in[0], d_in[1], d_in[2], wf, ei32, b32, x16, w1t, w2t, w3t, flags);

    const int wsz[20] = {32768,256,256,256,65536,256,256,256,16384,64,64,64,4096,64,65536,1024,4096,64,64,1};
    int woff[20]; int acc = 0;
    for (int s = 0; s < 20; s++) { woff[s] = acc; acc += wsz[s]; }
    const float *as1f = wf + woff[1], *ad1f = wf + woff[2], *b1f = wf + woff[3];
    const float *as2f = wf + woff[5], *ad2f = wf + woff[6], *b2f = wf + woff[7];
    const float *as3f = wf + woff[9], *ad3f = wf + woff[10], *b3f = wf + woff[11];
    const float *Wa1f = wf + woff[12], *ba1f = wf + woff[13], *Wa2f = wf + woff[14], *ba2f = wf + woff[15];
    const float *Wc1f = wf + woff[16], *bc1f = wf + woff[17], *Wc2f = wf + woff[18], *bc2f = wf + woff[19];

    // ---- CSR + graph boundaries (LDS atomics only, 16x replication) ----
    k_hist4<<<dim3(DNB, NSEG), 256, 0, stream>>>(ei32, partial);
    k_seg<<<(NN + 255) / 256, 256, 0, stream>>>(partial, deg, segpre);
    k_scan4<<<1, 1024, 0, stream>>>(deg, rowstart, b32, gstart);
    k_scatter3<<<dim3(DNB, NSEG), 256, 0, stream>>>(ei32, rowstart, segpre, ssrc);

    // ---- Layer 1: in 128 (x16), heads=4, out 64, concat ----
    k_gemm<128, 256><<<dim3(157, 4), 256, 0, stream>>>(x16, w1t, as1f, ad1f, actA16, sb, db);
    k_agg<4><<<NN, 256, 0, stream>>>(actA16, sb, db, rowstart, ssrc, b1f, actB16);

    // ---- Layer 2: in 256 (bf16), heads=4, out 64, concat ----
    k_gemm<256, 256><<<dim3(157, 4), 256, 0, stream>>>(actB16, w2t, as2f, ad2f, actA16, sb, db);
    k_agg<4><<<NN, 256, 0, stream>>>(actA16, sb, db, rowstart, ssrc, b2f, actB16);

    // ---- Layer 3: in 256 (bf16), heads=1, out 64 ----
    k_gemm<256, 64><<<dim3(157, 1), 256, 0, stream>>>(actB16, w3t, as3f, ad3f, actA16, sb, db);
    k_agg<1><<<NN, 64, 0, stream>>>(actA16, sb, db, rowstart, ssrc, b3f, actB16);

    // ---- fused pool + heads (bf16 features) ----
    k_final<<<BG, 256, 0, stream>>>(actB16, gstart,
                                    Wa1f, ba1f, Wc1f, bc1f, Wa2f, ba2f, Wc2f, bc2f, out);
}